// Round 3
// baseline (882.502 us; speedup 1.0000x reference)
//
#include <hip/hip_runtime.h>
#include <math.h>

// Problem constants
#define BB 2
#define SS 2048
#define DD 1024
#define HH 16
#define DKK 64
#define FKK 32

// ---------------------------------------------------------------------------
// Kernel 1: per-head M[h] = Wa[h] @ Wb[h] @ Wa2[h] @ Wb2[h]  (64x64 each)
// Wa[h] = W_A block h viewed [64][32]; Wb[h] = same block viewed [32][64].
// ---------------------------------------------------------------------------
__global__ __launch_bounds__(256) void prep_M_kernel(
    const float* __restrict__ WA, const float* __restrict__ WA2,
    float* __restrict__ Mout) {
  const int h = blockIdx.x;
  const float* A  = WA  + h * DKK * FKK;   // 2048 floats
  const float* A2 = WA2 + h * DKK * FKK;
  __shared__ float T1[DKK * DKK];
  __shared__ float T2[DKK * DKK];
  const int tid = threadIdx.x;
  for (int e = tid; e < DKK * DKK; e += 256) {
    int i = e >> 6, j = e & 63;
    float s1 = 0.f, s2 = 0.f;
    for (int c = 0; c < FKK; ++c) {
      s1 += A[i * FKK + c]  * A[c * DKK + j];    // Wa[i][c] * Wb[c][j]
      s2 += A2[i * FKK + c] * A2[c * DKK + j];
    }
    T1[e] = s1;
    T2[e] = s2;
  }
  __syncthreads();
  for (int e = tid; e < DKK * DKK; e += 256) {
    int i = e >> 6, j = e & 63;
    float s = 0.f;
    for (int k = 0; k < DKK; ++k) s += T1[i * DKK + k] * T2[k * DKK + j];
    Mout[h * DKK * DKK + e] = s;               // M[h][k][c] row-major
  }
}

// ---------------------------------------------------------------------------
// Kernel 2: C[M,N] = A[M,K] @ W[K,N] + bias   (fp32, 128x128 tile, 8x8 micro)
// As stored transposed [k][m] (pad 132 -> conflict-free b128 reads & writes).
// ---------------------------------------------------------------------------
__global__ __launch_bounds__(256, 2) void gemm_bias_kernel(
    const float* __restrict__ A, const float* __restrict__ W,
    const float* __restrict__ bias, float* __restrict__ C,
    int Kdim, int Ndim) {
  __shared__ float As[16 * 132];
  __shared__ float Bs[16 * 132];
  const int tid = threadIdx.x;
  const int tx = tid & 15, ty = tid >> 4;
  const int n0 = blockIdx.x * 128;
  const int m0 = blockIdx.y * 128;
  float acc[8][8] = {};
  for (int k0 = 0; k0 < Kdim; k0 += 16) {
    // stage A tile 128x16 transposed
#pragma unroll
    for (int it = 0; it < 2; ++it) {
      int f = it * 256 + tid;
      int row = f >> 2, c4 = f & 3;
      float4 av = *reinterpret_cast<const float4*>(
          A + (size_t)(m0 + row) * Kdim + k0 + c4 * 4);
      As[(c4 * 4 + 0) * 132 + row] = av.x;
      As[(c4 * 4 + 1) * 132 + row] = av.y;
      As[(c4 * 4 + 2) * 132 + row] = av.z;
      As[(c4 * 4 + 3) * 132 + row] = av.w;
    }
    // stage W tile 16x128 natural
#pragma unroll
    for (int it = 0; it < 2; ++it) {
      int f = it * 256 + tid;
      int kk = f >> 5, n4 = f & 31;
      *reinterpret_cast<float4*>(&Bs[kk * 132 + n4 * 4]) =
          *reinterpret_cast<const float4*>(
              W + (size_t)(k0 + kk) * Ndim + n0 + n4 * 4);
    }
    __syncthreads();
#pragma unroll
    for (int kk = 0; kk < 16; ++kk) {
      float a[8], bvec[8];
      *reinterpret_cast<float4*>(&a[0])    = *reinterpret_cast<const float4*>(&As[kk * 132 + ty * 8]);
      *reinterpret_cast<float4*>(&a[4])    = *reinterpret_cast<const float4*>(&As[kk * 132 + ty * 8 + 4]);
      *reinterpret_cast<float4*>(&bvec[0]) = *reinterpret_cast<const float4*>(&Bs[kk * 132 + tx * 8]);
      *reinterpret_cast<float4*>(&bvec[4]) = *reinterpret_cast<const float4*>(&Bs[kk * 132 + tx * 8 + 4]);
#pragma unroll
      for (int i = 0; i < 8; ++i)
#pragma unroll
        for (int j = 0; j < 8; ++j) acc[i][j] += a[i] * bvec[j];
    }
    __syncthreads();
  }
  float bj[8];
#pragma unroll
  for (int j = 0; j < 8; ++j) bj[j] = bias[n0 + tx * 8 + j];
#pragma unroll
  for (int i = 0; i < 8; ++i) {
    float* crow = C + (size_t)(m0 + ty * 8 + i) * Ndim + n0 + tx * 8;
    float4 o0, o1;
    o0.x = acc[i][0] + bj[0]; o0.y = acc[i][1] + bj[1];
    o0.z = acc[i][2] + bj[2]; o0.w = acc[i][3] + bj[3];
    o1.x = acc[i][4] + bj[4]; o1.y = acc[i][5] + bj[5];
    o1.z = acc[i][6] + bj[6]; o1.w = acc[i][7] + bj[7];
    *reinterpret_cast<float4*>(crow)     = o0;
    *reinterpret_cast<float4*>(crow + 4) = o1;
  }
}

// ---------------------------------------------------------------------------
// Kernel 3: fused flash attention (fp32), per block: one (b,h) and 64 q-rows.
//   Qp tile computed in prologue from q-tile @ M[h].
//   scores[r][t] = sum_c Qt[c][r]*Kt[c][t]  (both transposed in LDS, b128)
//   online softmax per row (row == 16 consecutive lanes, shfl_xor width 16)
//   P overlays the dead K buffer (saves 17 KB -> 51.2 KB LDS, 3 blocks/CU)
// ---------------------------------------------------------------------------
#define QT_ST 68   // stride (floats) for transposed Qt/Kt tiles
#define PS_ST 65   // stride for P ([t][r])

__global__ __launch_bounds__(256, 3) void flash_kernel(
    const float* __restrict__ q, const float* __restrict__ vp,
    const float* __restrict__ Mh, float* __restrict__ Og) {
  __shared__ float Qt[64 * QT_ST];     // Qp tile, [c][r]
  __shared__ float KtPs[64 * QT_ST];   // K tile [c][t]; later P [t][r]
  __shared__ float Vs[64 * 64];        // V tile [t][d]
  const int tid = threadIdx.x;
  const int tx = tid & 15;
  const int ty = tid >> 4;
  const int s0 = blockIdx.x * 64;
  const int bh = blockIdx.y;
  const int b = bh >> 4;
  const int h = bh & 15;
  const float* qbase = q  + (size_t)b * SS * DD + h * DKK;
  const float* vbase = vp + (size_t)b * SS * DD + h * DKK;

  // ---- prologue: Qt[c][r] = sum_k qT[k][r] * M[h][k][c] ----
#pragma unroll
  for (int it = 0; it < 4; ++it) {           // q tile transposed into KtPs
    int f = it * 256 + tid;
    int row = f >> 4, c4 = f & 15;
    float4 qv = *reinterpret_cast<const float4*>(
        qbase + (size_t)(s0 + row) * DD + c4 * 4);
    KtPs[(c4 * 4 + 0) * QT_ST + row] = qv.x;
    KtPs[(c4 * 4 + 1) * QT_ST + row] = qv.y;
    KtPs[(c4 * 4 + 2) * QT_ST + row] = qv.z;
    KtPs[(c4 * 4 + 3) * QT_ST + row] = qv.w;
  }
  const float* Mbase = Mh + h * DKK * DKK;
#pragma unroll
  for (int it = 0; it < 4; ++it) {           // M[h] natural into Vs
    int f = it * 256 + tid;
    int row = f >> 4, c4 = f & 15;
    *reinterpret_cast<float4*>(&Vs[row * 64 + c4 * 4]) =
        *reinterpret_cast<const float4*>(Mbase + row * DKK + c4 * 4);
  }
  __syncthreads();
  {
    float qa[4][4] = {};
    for (int k = 0; k < 64; ++k) {
      float a[4], mm[4];
      *reinterpret_cast<float4*>(a)  = *reinterpret_cast<const float4*>(&KtPs[k * QT_ST + ty * 4]);
      *reinterpret_cast<float4*>(mm) = *reinterpret_cast<const float4*>(&Vs[k * 64 + tx * 4]);
#pragma unroll
      for (int i = 0; i < 4; ++i)
#pragma unroll
        for (int j = 0; j < 4; ++j) qa[i][j] += a[i] * mm[j];
    }
#pragma unroll
    for (int i = 0; i < 4; ++i)
#pragma unroll
      for (int j = 0; j < 4; ++j)
        Qt[(tx * 4 + j) * QT_ST + ty * 4 + i] = qa[i][j];
  }
  __syncthreads();   // Qt visible; KtPs/Vs reads done -> safe to restage

  float mrun[4] = {-INFINITY, -INFINITY, -INFINITY, -INFINITY};
  float lrun[4] = {0.f, 0.f, 0.f, 0.f};
  float acc[4][4] = {};

  for (int t0 = 0; t0 < SS; t0 += 64) {
    // stage K tile (transposed) + V tile (natural)
#pragma unroll
    for (int it = 0; it < 4; ++it) {
      int f = it * 256 + tid;
      int row = f >> 4, c4 = f & 15;
      float4 kv = *reinterpret_cast<const float4*>(
          qbase + (size_t)(t0 + row) * DD + c4 * 4);
      KtPs[(c4 * 4 + 0) * QT_ST + row] = kv.x;
      KtPs[(c4 * 4 + 1) * QT_ST + row] = kv.y;
      KtPs[(c4 * 4 + 2) * QT_ST + row] = kv.z;
      KtPs[(c4 * 4 + 3) * QT_ST + row] = kv.w;
    }
#pragma unroll
    for (int it = 0; it < 4; ++it) {
      int f = it * 256 + tid;
      int row = f >> 4, c4 = f & 15;
      *reinterpret_cast<float4*>(&Vs[row * 64 + c4 * 4]) =
          *reinterpret_cast<const float4*>(
              vbase + (size_t)(t0 + row) * DD + c4 * 4);
    }
    __syncthreads();

    // scores 4x4 micro-tile, fp32
    float sc[4][4] = {};
#pragma unroll 4
    for (int c = 0; c < 64; ++c) {
      float qa[4], ka[4];
      *reinterpret_cast<float4*>(qa) = *reinterpret_cast<const float4*>(&Qt[c * QT_ST + ty * 4]);
      *reinterpret_cast<float4*>(ka) = *reinterpret_cast<const float4*>(&KtPs[c * QT_ST + tx * 4]);
#pragma unroll
      for (int i = 0; i < 4; ++i)
#pragma unroll
        for (int j = 0; j < 4; ++j) sc[i][j] += qa[i] * ka[j];
    }
    __syncthreads();   // all K reads done; KtPs becomes P

    float* Ps = KtPs;
#pragma unroll
    for (int i = 0; i < 4; ++i) {
      float tmax = fmaxf(fmaxf(sc[i][0], sc[i][1]), fmaxf(sc[i][2], sc[i][3]));
#pragma unroll
      for (int m = 1; m < 16; m <<= 1) tmax = fmaxf(tmax, __shfl_xor(tmax, m, 16));
      float mnew = fmaxf(mrun[i], tmax);
      float fac = __expf(mrun[i] - mnew);    // first tile: exp(-inf)=0
      mrun[i] = mnew;
      float ts = 0.f;
#pragma unroll
      for (int j = 0; j < 4; ++j) {
        float p = __expf(sc[i][j] - mnew);
        ts += p;
        Ps[(tx * 4 + j) * PS_ST + ty * 4 + i] = p;
      }
#pragma unroll
      for (int m = 1; m < 16; m <<= 1) ts += __shfl_xor(ts, m, 16);
      lrun[i] = lrun[i] * fac + ts;
#pragma unroll
      for (int j = 0; j < 4; ++j) acc[i][j] *= fac;
    }
    __syncthreads();   // P visible

    // PV accumulate
#pragma unroll 4
    for (int t = 0; t < 64; ++t) {
      float va[4];
      *reinterpret_cast<float4*>(va) = *reinterpret_cast<const float4*>(&Vs[t * 64 + tx * 4]);
      float p0 = Ps[t * PS_ST + ty * 4 + 0];
      float p1 = Ps[t * PS_ST + ty * 4 + 1];
      float p2 = Ps[t * PS_ST + ty * 4 + 2];
      float p3 = Ps[t * PS_ST + ty * 4 + 3];
#pragma unroll
      for (int j = 0; j < 4; ++j) {
        acc[0][j] += p0 * va[j];
        acc[1][j] += p1 * va[j];
        acc[2][j] += p2 * va[j];
        acc[3][j] += p3 * va[j];
      }
    }
    __syncthreads();   // PV reads done before restage
  }

  // epilogue: normalize, write concat layout [b][s][h*64+d]
  float* obase = Og + ((size_t)b * SS + s0) * DD + h * DKK;
#pragma unroll
  for (int i = 0; i < 4; ++i) {
    float rl = 1.f / lrun[i];
    float4 o;
    o.x = acc[i][0] * rl; o.y = acc[i][1] * rl;
    o.z = acc[i][2] * rl; o.w = acc[i][3] * rl;
    *reinterpret_cast<float4*>(obase + (size_t)(ty * 4 + i) * DD + tx * 4) = o;
  }
}

// ---------------------------------------------------------------------------
extern "C" void kernel_launch(void* const* d_in, const int* in_sizes, int n_in,
                              void* d_out, int out_size, void* d_ws, size_t ws_size,
                              hipStream_t stream) {
  (void)in_sizes; (void)n_in; (void)out_size; (void)ws_size;
  const float* q   = (const float*)d_in[0];
  // d_in[1] (k) is unused by the reference forward
  const float* v   = (const float*)d_in[2];
  const float* Wv  = (const float*)d_in[3];
  const float* bv  = (const float*)d_in[4];
  const float* WA  = (const float*)d_in[5];
  const float* WA2 = (const float*)d_in[6];
  const float* Wo  = (const float*)d_in[7];
  const float* bo  = (const float*)d_in[8];
  float* out = (float*)d_out;

  const size_t NROW = (size_t)BB * SS;            // 4096
  // workspace: vp (16.78 MB) | Og (16.78 MB) | M (256 KB)  ~= 33.8 MB
  float* vp = (float*)d_ws;
  float* Og = vp + NROW * DD;
  float* Mm = Og + NROW * DD;

  prep_M_kernel<<<dim3(HH), dim3(256), 0, stream>>>(WA, WA2, Mm);
  gemm_bias_kernel<<<dim3(DD / 128, NROW / 128), dim3(256), 0, stream>>>(
      v, Wv, bv, vp, DD, DD);
  flash_kernel<<<dim3(SS / 64, BB * HH), dim3(256), 0, stream>>>(
      q, vp, Mm, Og);
  gemm_bias_kernel<<<dim3(DD / 128, NROW / 128), dim3(256), 0, stream>>>(
      Og, Wo, bo, out, DD, DD);
}

// Round 9
// 641.530 us; speedup vs baseline: 1.3756x; 1.3756x over previous
//
#include <hip/hip_runtime.h>
#include <math.h>

// Problem constants
#define BB 2
#define SS 2048
#define DD 1024
#define HH 16
#define DKK 64
#define FKK 32

typedef unsigned short u16;
typedef __attribute__((ext_vector_type(8))) short short8;     // 8 bf16 (4 VGPR)
typedef __attribute__((ext_vector_type(8))) unsigned short ushort8;
typedef __attribute__((ext_vector_type(4))) float f32x4;

// fp32 -> bf16 round-to-nearest-even (normal values; inputs here are normal)
__device__ inline u16 f2bf(float x) {
  unsigned u = __float_as_uint(x);
  return (u16)((u + 0x7FFFu + ((u >> 16) & 1u)) >> 16);
}
__device__ inline float bf2f(u16 h) { return __uint_as_float(((unsigned)h) << 16); }

__device__ inline f32x4 mfma16(short8 a, short8 b, f32x4 c) {
  return __builtin_amdgcn_mfma_f32_16x16x32_bf16(a, b, c, 0, 0, 0);
}

// swizzled ushort index of 16B chunk (row stride 64 u16 = 128 B)
#define SWI(row, ch) (((row) << 6) + ((((ch) ^ ((row) & 7))) << 3))

// ---------------------------------------------------------------------------
// Kernel 1: per-head M[h] = Wa[h] @ Wb[h] @ Wa2[h] @ Wb2[h]  (64x64 each)
// ---------------------------------------------------------------------------
__global__ __launch_bounds__(256) void prep_M_kernel(
    const float* __restrict__ WA, const float* __restrict__ WA2,
    float* __restrict__ Mout) {
  const int h = blockIdx.x;
  const float* A  = WA  + h * DKK * FKK;
  const float* A2 = WA2 + h * DKK * FKK;
  __shared__ float T1[DKK * DKK];
  __shared__ float T2[DKK * DKK];
  const int tid = threadIdx.x;
  for (int e = tid; e < DKK * DKK; e += 256) {
    int i = e >> 6, j = e & 63;
    float s1 = 0.f, s2 = 0.f;
    for (int c = 0; c < FKK; ++c) {
      s1 += A[i * FKK + c]  * A[c * DKK + j];
      s2 += A2[i * FKK + c] * A2[c * DKK + j];
    }
    T1[e] = s1;
    T2[e] = s2;
  }
  __syncthreads();
  for (int e = tid; e < DKK * DKK; e += 256) {
    int i = e >> 6, j = e & 63;
    float s = 0.f;
    for (int k = 0; k < DKK; ++k) s += T1[i * DKK + k] * T2[k * DKK + j];
    Mout[h * DKK * DKK + e] = s;   // M[h][k][c]
  }
}

// ---------------------------------------------------------------------------
// Kernel 2: Qp = blockdiag(q @ M[h]); emit 3-way bf16 splits of Qp AND q,
// layout [plane][b][h][s][64c] (rows of 64 bf16 = 128 B).
// ---------------------------------------------------------------------------
__global__ __launch_bounds__(256) void qp_split_kernel(
    const float* __restrict__ q, const float* __restrict__ Mh,
    u16* __restrict__ QpS, u16* __restrict__ qS) {
  __shared__ float At[64 * 68];   // q-slice transposed [c][r]
  __shared__ float Ms[64 * 64];   // M[h] [k][c]
  const int tid = threadIdx.x;
  const int tx = tid & 15, ty = tid >> 4;
  const int s0 = blockIdx.x * 64;
  const int bh = blockIdx.y;
  const int b = bh >> 4, h = bh & 15;
  const float* qb = q + (size_t)b * SS * DD + h * DKK;
#pragma unroll
  for (int it = 0; it < 4; ++it) {
    int f = it * 256 + tid;
    int r = f >> 4, c4 = f & 15;
    float4 v = *reinterpret_cast<const float4*>(qb + (size_t)(s0 + r) * DD + c4 * 4);
    At[(c4 * 4 + 0) * 68 + r] = v.x;
    At[(c4 * 4 + 1) * 68 + r] = v.y;
    At[(c4 * 4 + 2) * 68 + r] = v.z;
    At[(c4 * 4 + 3) * 68 + r] = v.w;
  }
  const float* Mb = Mh + h * DKK * DKK;
#pragma unroll
  for (int it = 0; it < 4; ++it) {
    int f = it * 256 + tid;
    int k = f >> 4, c4 = f & 15;
    *reinterpret_cast<float4*>(&Ms[k * 64 + c4 * 4]) =
        *reinterpret_cast<const float4*>(Mb + k * DKK + c4 * 4);
  }
  __syncthreads();
  float acc[4][4] = {};
  for (int k = 0; k < 64; ++k) {
    float a[4], m[4];
    *reinterpret_cast<float4*>(a) = *reinterpret_cast<const float4*>(&At[k * 68 + ty * 4]);
    *reinterpret_cast<float4*>(m) = *reinterpret_cast<const float4*>(&Ms[k * 64 + tx * 4]);
#pragma unroll
    for (int i = 0; i < 4; ++i)
#pragma unroll
      for (int j = 0; j < 4; ++j) acc[i][j] += a[i] * m[j];
  }
  const size_t planeQ = (size_t)BB * HH * SS * 64;
  const size_t base = (size_t)bh * SS * 64;
#pragma unroll
  for (int i = 0; i < 4; ++i)
#pragma unroll
    for (int j = 0; j < 4; ++j) {
      size_t ad = base + (size_t)(s0 + ty * 4 + i) * 64 + tx * 4 + j;
      float x = acc[i][j];
      u16 h0 = f2bf(x); float f0 = bf2f(h0);
      u16 h1 = f2bf(x - f0); float f1 = bf2f(h1);
      u16 h2 = f2bf(x - f0 - f1);
      QpS[ad] = h0; QpS[planeQ + ad] = h1; QpS[2 * planeQ + ad] = h2;
      float y = At[(tx * 4 + j) * 68 + (ty * 4 + i)];
      u16 g0 = f2bf(y); float e0 = bf2f(g0);
      u16 g1 = f2bf(y - e0); float e1 = bf2f(g1);
      u16 g2 = f2bf(y - e0 - e1);
      qS[ad] = g0; qS[planeQ + ad] = g1; qS[2 * planeQ + ad] = g2;
    }
}

// ---------------------------------------------------------------------------
// Kernel 3: vp GEMM (v @ Wv + bv), fp32 compute; epilogue writes V TRANSPOSED
// as 2-way bf16 split planes: vts[p][b][h][dk][t]  (t contiguous).
// ---------------------------------------------------------------------------
__global__ __launch_bounds__(256, 2) void gemm_vts_kernel(
    const float* __restrict__ A, const float* __restrict__ W,
    const float* __restrict__ bias, u16* __restrict__ vts) {
  __shared__ float As[16 * 132];
  __shared__ float Bs[16 * 132];
  const int tid = threadIdx.x;
  const int tx = tid & 15, ty = tid >> 4;
  const int n0 = blockIdx.x * 128;
  const int m0 = blockIdx.y * 128;
  float acc[8][8] = {};
  for (int k0 = 0; k0 < DD; k0 += 16) {
#pragma unroll
    for (int it = 0; it < 2; ++it) {
      int f = it * 256 + tid;
      int row = f >> 2, c4 = f & 3;
      float4 av = *reinterpret_cast<const float4*>(
          A + (size_t)(m0 + row) * DD + k0 + c4 * 4);
      As[(c4 * 4 + 0) * 132 + row] = av.x;
      As[(c4 * 4 + 1) * 132 + row] = av.y;
      As[(c4 * 4 + 2) * 132 + row] = av.z;
      As[(c4 * 4 + 3) * 132 + row] = av.w;
    }
#pragma unroll
    for (int it = 0; it < 2; ++it) {
      int f = it * 256 + tid;
      int kk = f >> 5, n4 = f & 31;
      *reinterpret_cast<float4*>(&Bs[kk * 132 + n4 * 4]) =
          *reinterpret_cast<const float4*>(W + (size_t)(k0 + kk) * DD + n0 + n4 * 4);
    }
    __syncthreads();
#pragma unroll
    for (int kk = 0; kk < 16; ++kk) {
      float a[8], bvec[8];
      *reinterpret_cast<float4*>(&a[0])    = *reinterpret_cast<const float4*>(&As[kk * 132 + ty * 8]);
      *reinterpret_cast<float4*>(&a[4])    = *reinterpret_cast<const float4*>(&As[kk * 132 + ty * 8 + 4]);
      *reinterpret_cast<float4*>(&bvec[0]) = *reinterpret_cast<const float4*>(&Bs[kk * 132 + tx * 8]);
      *reinterpret_cast<float4*>(&bvec[4]) = *reinterpret_cast<const float4*>(&Bs[kk * 132 + tx * 8 + 4]);
#pragma unroll
      for (int i = 0; i < 8; ++i)
#pragma unroll
        for (int j = 0; j < 8; ++j) acc[i][j] += a[i] * bvec[j];
    }
    __syncthreads();
  }
  const size_t planeV = (size_t)BB * HH * 64 * SS;
  float bj[8];
#pragma unroll
  for (int j = 0; j < 8; ++j) bj[j] = bias[n0 + tx * 8 + j];
  const int m = m0 + ty * 8;
  const int b_ = m >> 11, t = m & 2047;
#pragma unroll
  for (int j = 0; j < 8; ++j) {
    int n = n0 + tx * 8 + j;
    int hh = n >> 6, dk = n & 63;
    ushort8 hi, lo;
#pragma unroll
    for (int i = 0; i < 8; ++i) {
      float x = acc[i][j] + bj[j];
      u16 a0 = f2bf(x);
      hi[i] = a0;
      lo[i] = f2bf(x - bf2f(a0));
    }
    size_t ad = ((size_t)b_ * HH + hh) * ((size_t)64 * SS) + (size_t)dk * SS + t;
    *reinterpret_cast<ushort8*>(&vts[ad]) = hi;
    *reinterpret_cast<ushort8*>(&vts[planeV + ad]) = lo;
  }
}

// ---------------------------------------------------------------------------
// Kernel 4: flash attention via split-bf16 MFMA.
// Block = (64 q-rows, one (b,h)); 4 waves, wave w owns rows [16w,16w+16).
// QK^T: 8 split-term MFMAs per (col-tile,K-step) -> fp32-accurate logits.
// PV:   3 split-term MFMAs (P 2-split x V 2-split).
// All LDS tiles XOR-swizzled (chunk^row&7): conflict-free ds_read_b128.
// ---------------------------------------------------------------------------
__global__ __launch_bounds__(256, 2) void flash_mfma_kernel(
    const u16* __restrict__ QpS, const u16* __restrict__ qS,
    const u16* __restrict__ vts, float* __restrict__ Og) {
  __shared__ u16 Qs[3][4096];    // Qp splits [row][c], swizzled      24 KB
  __shared__ u16 KPs[3][4096];   // K splits; [0..1] reused as P      24 KB
  __shared__ u16 Vs[2][4096];    // V splits [d][t], swizzled         16 KB
  const int tid = threadIdx.x;
  const int l = tid & 63;
  const int w = tid >> 6;
  const int lm = l & 15;
  const int akg = l >> 4;
  const int s0 = blockIdx.x * 64;
  const int bh = blockIdx.y;
  const size_t planeQ = (size_t)BB * HH * SS * 64;
  const u16* Qb = QpS + (size_t)bh * SS * 64;
  const u16* Kb = qS  + (size_t)bh * SS * 64;
  const u16* Vb = vts + (size_t)bh * 64 * SS;

  // prologue: stage Qp tile (3 planes)
#pragma unroll
  for (int p = 0; p < 3; ++p)
#pragma unroll
    for (int it = 0; it < 2; ++it) {
      int f = it * 256 + tid;
      int row = f >> 3, ch = f & 7;
      ushort8 vv = *reinterpret_cast<const ushort8*>(
          Qb + p * planeQ + (size_t)(s0 + row) * 64 + ch * 8);
      *reinterpret_cast<ushort8*>(&Qs[p][SWI(row, ch)]) = vv;
    }
  __syncthreads();
  short8 qa[3][2];
  {
    int arow = w * 16 + lm;
#pragma unroll
    for (int p = 0; p < 3; ++p)
#pragma unroll
      for (int ks = 0; ks < 2; ++ks)
        qa[p][ks] = *reinterpret_cast<const short8*>(&Qs[p][SWI(arow, ks * 4 + akg)]);
  }

  float mrun[4], lrun[4];
  f32x4 O[4];
  const f32x4 zero4 = {0.f, 0.f, 0.f, 0.f};
#pragma unroll
  for (int r = 0; r < 4; ++r) { mrun[r] = -INFINITY; lrun[r] = 0.f; O[r] = zero4; }

  for (int t0 = 0; t0 < SS; t0 += 64) {
    // stage K (3 planes) + V (2 planes)
#pragma unroll
    for (int p = 0; p < 3; ++p)
#pragma unroll
      for (int it = 0; it < 2; ++it) {
        int f = it * 256 + tid;
        int row = f >> 3, ch = f & 7;
        ushort8 vv = *reinterpret_cast<const ushort8*>(
            Kb + p * planeQ + (size_t)(t0 + row) * 64 + ch * 8);
        *reinterpret_cast<ushort8*>(&KPs[p][SWI(row, ch)]) = vv;
      }
#pragma unroll
    for (int p = 0; p < 2; ++p)
#pragma unroll
      for (int it = 0; it < 2; ++it) {
        int f = it * 256 + tid;
        int row = f >> 3, ch = f & 7;   // row = d
        ushort8 vv = *reinterpret_cast<const ushort8*>(
            Vb + p * planeQ + (size_t)row * SS + t0 + ch * 8);
        *reinterpret_cast<ushort8*>(&Vs[p][SWI(row, ch)]) = vv;
      }
    __syncthreads();

    // S = Qp q^T, 8 split terms (error ~2^-31 relative)
    f32x4 S[4];
#pragma unroll
    for (int ct = 0; ct < 4; ++ct) {
      int brow = ct * 16 + lm;
      short8 kb[3][2];
#pragma unroll
      for (int p = 0; p < 3; ++p)
#pragma unroll
        for (int ks = 0; ks < 2; ++ks)
          kb[p][ks] = *reinterpret_cast<const short8*>(&KPs[p][SWI(brow, ks * 4 + akg)]);
      f32x4 d = zero4;
#pragma unroll
      for (int ks = 0; ks < 2; ++ks) {
        d = mfma16(qa[0][ks], kb[0][ks], d);
        d = mfma16(qa[0][ks], kb[1][ks], d);
        d = mfma16(qa[1][ks], kb[0][ks], d);
        d = mfma16(qa[0][ks], kb[2][ks], d);
        d = mfma16(qa[1][ks], kb[1][ks], d);
        d = mfma16(qa[2][ks], kb[0][ks], d);
        d = mfma16(qa[1][ks], kb[2][ks], d);
        d = mfma16(qa[2][ks], kb[1][ks], d);
      }
      S[ct] = d;
    }
    __syncthreads();   // all K reads complete; KPs[0..1] become P planes

    // online softmax; D layout: row=(l>>4)*4+r, col=l&15 (per m89)
    float fac[4];
#pragma unroll
    for (int r = 0; r < 4; ++r) {
      float v0 = S[0][r], v1 = S[1][r], v2 = S[2][r], v3 = S[3][r];
      float tmax = fmaxf(fmaxf(v0, v1), fmaxf(v2, v3));
#pragma unroll
      for (int m = 1; m < 16; m <<= 1) tmax = fmaxf(tmax, __shfl_xor(tmax, m, 16));
      float mnew = fmaxf(mrun[r], tmax);
      fac[r] = __expf(mrun[r] - mnew);
      mrun[r] = mnew;
      float pv[4];
      pv[0] = __expf(v0 - mnew); pv[1] = __expf(v1 - mnew);
      pv[2] = __expf(v2 - mnew); pv[3] = __expf(v3 - mnew);
      float ts = (pv[0] + pv[1]) + (pv[2] + pv[3]);
#pragma unroll
      for (int m = 1; m < 16; m <<= 1) ts += __shfl_xor(ts, m, 16);
      lrun[r] = lrun[r] * fac[r] + ts;
      int prow = w * 16 + akg * 4 + r;
      int chb = lm >> 3;
      int e = l & 7;
#pragma unroll
      for (int ct = 0; ct < 4; ++ct) {
        int idx = SWI(prow, ct * 2 + chb) + e;
        u16 hi = f2bf(pv[ct]);
        KPs[0][idx] = hi;
        KPs[1][idx] = f2bf(pv[ct] - bf2f(hi));
      }
    }
#pragma unroll
    for (int dt = 0; dt < 4; ++dt) {
      f32x4 o = O[dt];
      o[0] *= fac[0]; o[1] *= fac[1]; o[2] *= fac[2]; o[3] *= fac[3];
      O[dt] = o;
    }
    // P rows [16w,16w+16) written & read only by wave w -> in-wave lgkmcnt
    // ordering suffices, no barrier needed before PV.

    short8 pa[2][2];
    {
      int arow = w * 16 + lm;
#pragma unroll
      for (int p = 0; p < 2; ++p)
#pragma unroll
        for (int ks = 0; ks < 2; ++ks)
          pa[p][ks] = *reinterpret_cast<const short8*>(&KPs[p][SWI(arow, ks * 4 + akg)]);
    }
#pragma unroll
    for (int dt = 0; dt < 4; ++dt) {
      int brow = dt * 16 + lm;
#pragma unroll
      for (int ks = 0; ks < 2; ++ks) {
        short8 v0 = *reinterpret_cast<const short8*>(&Vs[0][SWI(brow, ks * 4 + akg)]);
        short8 v1 = *reinterpret_cast<const short8*>(&Vs[1][SWI(brow, ks * 4 + akg)]);
        O[dt] = mfma16(pa[0][ks], v0, O[dt]);
        O[dt] = mfma16(pa[0][ks], v1, O[dt]);
        O[dt] = mfma16(pa[1][ks], v0, O[dt]);
      }
    }
    __syncthreads();   // PV + P reads done; safe to restage next tile
  }

  // epilogue: normalize, write concat layout [b][s][h*64+d]
  const int b = bh >> 4, h = bh & 15;
  float* ob = Og + ((size_t)b * SS + s0) * DD + h * 64;
#pragma unroll
  for (int r = 0; r < 4; ++r) {
    float rl = 1.f / lrun[r];
    int orow = w * 16 + akg * 4 + r;
#pragma unroll
    for (int dt = 0; dt < 4; ++dt)
      ob[(size_t)orow * DD + dt * 16 + lm] = O[dt][r] * rl;
  }
}

// ---------------------------------------------------------------------------
// Kernel 5: out GEMM (fp32), unchanged from passing R3 version
// ---------------------------------------------------------------------------
__global__ __launch_bounds__(256, 2) void gemm_bias_kernel(
    const float* __restrict__ A, const float* __restrict__ W,
    const float* __restrict__ bias, float* __restrict__ C,
    int Kdim, int Ndim) {
  __shared__ float As[16 * 132];
  __shared__ float Bs[16 * 132];
  const int tid = threadIdx.x;
  const int tx = tid & 15, ty = tid >> 4;
  const int n0 = blockIdx.x * 128;
  const int m0 = blockIdx.y * 128;
  float acc[8][8] = {};
  for (int k0 = 0; k0 < Kdim; k0 += 16) {
#pragma unroll
    for (int it = 0; it < 2; ++it) {
      int f = it * 256 + tid;
      int row = f >> 2, c4 = f & 3;
      float4 av = *reinterpret_cast<const float4*>(
          A + (size_t)(m0 + row) * Kdim + k0 + c4 * 4);
      As[(c4 * 4 + 0) * 132 + row] = av.x;
      As[(c4 * 4 + 1) * 132 + row] = av.y;
      As[(c4 * 4 + 2) * 132 + row] = av.z;
      As[(c4 * 4 + 3) * 132 + row] = av.w;
    }
#pragma unroll
    for (int it = 0; it < 2; ++it) {
      int f = it * 256 + tid;
      int kk = f >> 5, n4 = f & 31;
      *reinterpret_cast<float4*>(&Bs[kk * 132 + n4 * 4]) =
          *reinterpret_cast<const float4*>(W + (size_t)(k0 + kk) * Ndim + n0 + n4 * 4);
    }
    __syncthreads();
#pragma unroll
    for (int kk = 0; kk < 16; ++kk) {
      float a[8], bvec[8];
      *reinterpret_cast<float4*>(&a[0])    = *reinterpret_cast<const float4*>(&As[kk * 132 + ty * 8]);
      *reinterpret_cast<float4*>(&a[4])    = *reinterpret_cast<const float4*>(&As[kk * 132 + ty * 8 + 4]);
      *reinterpret_cast<float4*>(&bvec[0]) = *reinterpret_cast<const float4*>(&Bs[kk * 132 + tx * 8]);
      *reinterpret_cast<float4*>(&bvec[4]) = *reinterpret_cast<const float4*>(&Bs[kk * 132 + tx * 8 + 4]);
#pragma unroll
      for (int i = 0; i < 8; ++i)
#pragma unroll
        for (int j = 0; j < 8; ++j) acc[i][j] += a[i] * bvec[j];
    }
    __syncthreads();
  }
  float bj[8];
#pragma unroll
  for (int j = 0; j < 8; ++j) bj[j] = bias[n0 + tx * 8 + j];
#pragma unroll
  for (int i = 0; i < 8; ++i) {
    float* crow = C + (size_t)(m0 + ty * 8 + i) * Ndim + n0 + tx * 8;
    float4 o0, o1;
    o0.x = acc[i][0] + bj[0]; o0.y = acc[i][1] + bj[1];
    o0.z = acc[i][2] + bj[2]; o0.w = acc[i][3] + bj[3];
    o1.x = acc[i][4] + bj[4]; o1.y = acc[i][5] + bj[5];
    o1.z = acc[i][6] + bj[6]; o1.w = acc[i][7] + bj[7];
    *reinterpret_cast<float4*>(crow)     = o0;
    *reinterpret_cast<float4*>(crow + 4) = o1;
  }
}

// ---------------------------------------------------------------------------
extern "C" void kernel_launch(void* const* d_in, const int* in_sizes, int n_in,
                              void* d_out, int out_size, void* d_ws, size_t ws_size,
                              hipStream_t stream) {
  (void)in_sizes; (void)n_in; (void)out_size; (void)ws_size;
  const float* q   = (const float*)d_in[0];
  // d_in[1] (k) unused by the reference forward
  const float* v   = (const float*)d_in[2];
  const float* Wv  = (const float*)d_in[3];
  const float* bv  = (const float*)d_in[4];
  const float* WA  = (const float*)d_in[5];
  const float* WA2 = (const float*)d_in[6];
  const float* Wo  = (const float*)d_in[7];
  const float* bo  = (const float*)d_in[8];
  float* out = (float*)d_out;

  // ws layout (~84.2 MB):
  //   Mm 256 KB | QpS 25.2 MB | qS 25.2 MB | vts 16.8 MB | Og 16.8 MB
  const size_t planeQ = (size_t)BB * HH * SS * 64;   // 4,194,304 elems
  char* wsb = (char*)d_ws;
  float* Mm = (float*)wsb;
  u16* QpS = (u16*)(wsb + (1 << 18));
  u16* qS  = QpS + 3 * planeQ;
  u16* vts = qS + 3 * planeQ;
  float* Og = (float*)(vts + 2 * planeQ);

  prep_M_kernel<<<dim3(HH), dim3(256), 0, stream>>>(WA, WA2, Mm);
  qp_split_kernel<<<dim3(SS / 64, BB * HH), dim3(256), 0, stream>>>(q, Mm, QpS, qS);
  gemm_vts_kernel<<<dim3(DD / 128, (BB * SS) / 128), dim3(256), 0, stream>>>(v, Wv, bv, vts);
  flash_mfma_kernel<<<dim3(SS / 64, BB * HH), dim3(256), 0, stream>>>(QpS, qS, vts, Og);
  gemm_bias_kernel<<<dim3(DD / 128, (BB * SS) / 128), dim3(256), 0, stream>>>(
      Og, Wo, bo, out, DD, DD);
}

// Round 11
// 430.607 us; speedup vs baseline: 2.0494x; 1.4898x over previous
//
#include <hip/hip_runtime.h>
#include <math.h>

// Problem constants
#define BB 2
#define SS 2048
#define DD 1024
#define HH 16
#define DKK 64
#define FKK 32

typedef unsigned short u16;
typedef __attribute__((ext_vector_type(8))) short short8;     // 8 bf16 (4 VGPR)
typedef __attribute__((ext_vector_type(8))) unsigned short ushort8;
typedef __attribute__((ext_vector_type(4))) unsigned short u16x4;
typedef __attribute__((ext_vector_type(4))) float f32x4;

// fp32 -> bf16 round-to-nearest-even
__device__ inline u16 f2bf(float x) {
  unsigned u = __float_as_uint(x);
  return (u16)((u + 0x7FFFu + ((u >> 16) & 1u)) >> 16);
}
__device__ inline float bf2f(u16 h) { return __uint_as_float(((unsigned)h) << 16); }

__device__ inline f32x4 mfma16(short8 a, short8 b, f32x4 c) {
  return __builtin_amdgcn_mfma_f32_16x16x32_bf16(a, b, c, 0, 0, 0);
}

// swizzled ushort index of 16B chunk (row stride 64 u16 = 128 B); HW-verified
// conflict-free in R9 (SQ_LDS_BANK_CONFLICT = 0).
#define SWI(row, ch) (((row) << 6) + ((((ch) ^ ((row) & 7))) << 3))

// ---------------------------------------------------------------------------
// Kernel 1: per-head M[h] = Wa[h] @ Wb[h] @ Wa2[h] @ Wb2[h]  (64x64 each)
// ---------------------------------------------------------------------------
__global__ __launch_bounds__(256) void prep_M_kernel(
    const float* __restrict__ WA, const float* __restrict__ WA2,
    float* __restrict__ Mout) {
  const int h = blockIdx.x;
  const float* A  = WA  + h * DKK * FKK;
  const float* A2 = WA2 + h * DKK * FKK;
  __shared__ float T1[DKK * DKK];
  __shared__ float T2[DKK * DKK];
  const int tid = threadIdx.x;
  for (int e = tid; e < DKK * DKK; e += 256) {
    int i = e >> 6, j = e & 63;
    float s1 = 0.f, s2 = 0.f;
    for (int c = 0; c < FKK; ++c) {
      s1 += A[i * FKK + c]  * A[c * DKK + j];
      s2 += A2[i * FKK + c] * A2[c * DKK + j];
    }
    T1[e] = s1;
    T2[e] = s2;
  }
  __syncthreads();
  for (int e = tid; e < DKK * DKK; e += 256) {
    int i = e >> 6, j = e & 63;
    float s = 0.f;
    for (int k = 0; k < DKK; ++k) s += T1[i * DKK + k] * T2[k * DKK + j];
    Mout[h * DKK * DKK + e] = s;   // M[h][k][c]
  }
}

// ---------------------------------------------------------------------------
// Kernel 2: Qp = blockdiag(q @ M[h]); emit 3-way bf16 splits of Qp AND q.
// ---------------------------------------------------------------------------
__global__ __launch_bounds__(256) void qp_split_kernel(
    const float* __restrict__ q, const float* __restrict__ Mh,
    u16* __restrict__ QpS, u16* __restrict__ qS) {
  __shared__ float At[64 * 68];   // q-slice transposed [c][r]
  __shared__ float Ms[64 * 64];   // M[h] [k][c]
  const int tid = threadIdx.x;
  const int tx = tid & 15, ty = tid >> 4;
  const int s0 = blockIdx.x * 64;
  const int bh = blockIdx.y;
  const int b = bh >> 4, h = bh & 15;
  const float* qb = q + (size_t)b * SS * DD + h * DKK;
#pragma unroll
  for (int it = 0; it < 4; ++it) {
    int f = it * 256 + tid;
    int r = f >> 4, c4 = f & 15;
    float4 v = *reinterpret_cast<const float4*>(qb + (size_t)(s0 + r) * DD + c4 * 4);
    At[(c4 * 4 + 0) * 68 + r] = v.x;
    At[(c4 * 4 + 1) * 68 + r] = v.y;
    At[(c4 * 4 + 2) * 68 + r] = v.z;
    At[(c4 * 4 + 3) * 68 + r] = v.w;
  }
  const float* Mb = Mh + h * DKK * DKK;
#pragma unroll
  for (int it = 0; it < 4; ++it) {
    int f = it * 256 + tid;
    int k = f >> 4, c4 = f & 15;
    *reinterpret_cast<float4*>(&Ms[k * 64 + c4 * 4]) =
        *reinterpret_cast<const float4*>(Mb + k * DKK + c4 * 4);
  }
  __syncthreads();
  float acc[4][4] = {};
  for (int k = 0; k < 64; ++k) {
    float a[4], m[4];
    *reinterpret_cast<float4*>(a) = *reinterpret_cast<const float4*>(&At[k * 68 + ty * 4]);
    *reinterpret_cast<float4*>(m) = *reinterpret_cast<const float4*>(&Ms[k * 64 + tx * 4]);
#pragma unroll
    for (int i = 0; i < 4; ++i)
#pragma unroll
      for (int j = 0; j < 4; ++j) acc[i][j] += a[i] * m[j];
  }
  const size_t planeQ = (size_t)BB * HH * SS * 64;
  const size_t base = (size_t)bh * SS * 64;
#pragma unroll
  for (int i = 0; i < 4; ++i)
#pragma unroll
    for (int j = 0; j < 4; ++j) {
      size_t ad = base + (size_t)(s0 + ty * 4 + i) * 64 + tx * 4 + j;
      float x = acc[i][j];
      u16 h0 = f2bf(x); float f0 = bf2f(h0);
      u16 h1 = f2bf(x - f0); float f1 = bf2f(h1);
      u16 h2 = f2bf(x - f0 - f1);
      QpS[ad] = h0; QpS[planeQ + ad] = h1; QpS[2 * planeQ + ad] = h2;
      float y = At[(tx * 4 + j) * 68 + (ty * 4 + i)];
      u16 g0 = f2bf(y); float e0 = bf2f(g0);
      u16 g1 = f2bf(y - e0); float e1 = bf2f(g1);
      u16 g2 = f2bf(y - e0 - e1);
      qS[ad] = g0; qS[planeQ + ad] = g1; qS[2 * planeQ + ad] = g2;
    }
}

// ---------------------------------------------------------------------------
// Kernel 3: elementwise 2-way bf16 split (for v)
// ---------------------------------------------------------------------------
__global__ __launch_bounds__(256) void split2_kernel(
    const float* __restrict__ src, u16* __restrict__ hi, u16* __restrict__ lo) {
  size_t i = ((size_t)blockIdx.x * 256 + threadIdx.x) * 8;
  float4 x0 = *reinterpret_cast<const float4*>(src + i);
  float4 x1 = *reinterpret_cast<const float4*>(src + i + 4);
  float xs[8] = {x0.x, x0.y, x0.z, x0.w, x1.x, x1.y, x1.z, x1.w};
  ushort8 h, l;
#pragma unroll
  for (int j = 0; j < 8; ++j) {
    u16 a = f2bf(xs[j]);
    h[j] = a;
    l[j] = f2bf(xs[j] - bf2f(a));
  }
  *reinterpret_cast<ushort8*>(hi + i) = h;
  *reinterpret_cast<ushort8*>(lo + i) = l;
}

// ---------------------------------------------------------------------------
// Kernel 4: W[1024][1024] fp32 -> TRANSPOSED 2-way bf16 splits Wt[n][k]
// (B-operand of MFMA loads like A-operand of the transposed matrix)
// ---------------------------------------------------------------------------
__global__ __launch_bounds__(256) void split_tr_kernel(
    const float* __restrict__ W, u16* __restrict__ hi, u16* __restrict__ lo) {
  __shared__ float T[64][65];
  const int tid = threadIdx.x;
  const int k0 = blockIdx.y * 64, n0 = blockIdx.x * 64;
#pragma unroll
  for (int it = 0; it < 4; ++it) {
    int f = it * 256 + tid;
    int r = f >> 4, c4 = f & 15;
    float4 x = *reinterpret_cast<const float4*>(W + (size_t)(k0 + r) * 1024 + n0 + c4 * 4);
    T[r][c4 * 4 + 0] = x.x; T[r][c4 * 4 + 1] = x.y;
    T[r][c4 * 4 + 2] = x.z; T[r][c4 * 4 + 3] = x.w;
  }
  __syncthreads();
#pragma unroll
  for (int it = 0; it < 2; ++it) {
    int f = it * 256 + tid;
    int nr = f >> 3, ch = f & 7;
    ushort8 h, l;
#pragma unroll
    for (int j = 0; j < 8; ++j) {
      float x = T[ch * 8 + j][nr];
      u16 a = f2bf(x);
      h[j] = a;
      l[j] = f2bf(x - bf2f(a));
    }
    size_t ad = (size_t)(n0 + nr) * 1024 + k0 + ch * 8;
    *reinterpret_cast<ushort8*>(hi + ad) = h;
    *reinterpret_cast<ushort8*>(lo + ad) = l;
  }
}

// ---------------------------------------------------------------------------
// Kernel 5: split-bf16 MFMA GEMM.  C[4096,1024] = A @ Wt^T + bias.
// BM=128 BN=64 BK=64; 4 waves (2x2); 3 split terms (hi*hi, hi*lo, lo*hi).
// EPI=0: fp32 C write.  EPI=1: vts split-plane transposed write.
// ---------------------------------------------------------------------------
template <int EPI>
__global__ __launch_bounds__(256, 3) void gemm_mfma_kernel(
    const u16* __restrict__ Ahi, const u16* __restrict__ Alo,
    const u16* __restrict__ Wthi, const u16* __restrict__ Wtlo,
    const float* __restrict__ bias, float* __restrict__ Cf,
    u16* __restrict__ Cs) {
  __shared__ u16 As[2][8192];   // [plane][128 rows x 64k] swizzled, 32 KB
  __shared__ u16 Ws[2][4096];   // [plane][64 n-rows x 64k] swizzled, 16 KB
  const int tid = threadIdx.x;
  const int l = tid & 63, w = tid >> 6;
  const int lm = l & 15, akg = l >> 4;
  const int wm = w >> 1, wn = w & 1;
  const int n0 = blockIdx.x * 64, m0 = blockIdx.y * 128;
  const f32x4 zero4 = {0.f, 0.f, 0.f, 0.f};
  f32x4 acc[4][2];
#pragma unroll
  for (int mf = 0; mf < 4; ++mf)
#pragma unroll
    for (int nf = 0; nf < 2; ++nf) acc[mf][nf] = zero4;

  for (int k0 = 0; k0 < 1024; k0 += 64) {
#pragma unroll
    for (int it = 0; it < 4; ++it) {
      int f = it * 256 + tid;
      int row = f >> 3, ch = f & 7;
      size_t src = (size_t)(m0 + row) * 1024 + k0 + ch * 8;
      *reinterpret_cast<ushort8*>(&As[0][SWI(row, ch)]) =
          *reinterpret_cast<const ushort8*>(Ahi + src);
      *reinterpret_cast<ushort8*>(&As[1][SWI(row, ch)]) =
          *reinterpret_cast<const ushort8*>(Alo + src);
    }
#pragma unroll
    for (int it = 0; it < 2; ++it) {
      int f = it * 256 + tid;
      int row = f >> 3, ch = f & 7;
      size_t src = (size_t)(n0 + row) * 1024 + k0 + ch * 8;
      *reinterpret_cast<ushort8*>(&Ws[0][SWI(row, ch)]) =
          *reinterpret_cast<const ushort8*>(Wthi + src);
      *reinterpret_cast<ushort8*>(&Ws[1][SWI(row, ch)]) =
          *reinterpret_cast<const ushort8*>(Wtlo + src);
    }
    __syncthreads();
#pragma unroll
    for (int ks = 0; ks < 2; ++ks) {
      short8 a[4][2], b[2][2];
#pragma unroll
      for (int mf = 0; mf < 4; ++mf)
#pragma unroll
        for (int p = 0; p < 2; ++p)
          a[mf][p] = *reinterpret_cast<const short8*>(
              &As[p][SWI(wm * 64 + mf * 16 + lm, ks * 4 + akg)]);
#pragma unroll
      for (int nf = 0; nf < 2; ++nf)
#pragma unroll
        for (int p = 0; p < 2; ++p)
          b[nf][p] = *reinterpret_cast<const short8*>(
              &Ws[p][SWI(wn * 32 + nf * 16 + lm, ks * 4 + akg)]);
#pragma unroll
      for (int mf = 0; mf < 4; ++mf)
#pragma unroll
        for (int nf = 0; nf < 2; ++nf) {
          acc[mf][nf] = mfma16(a[mf][0], b[nf][0], acc[mf][nf]);
          acc[mf][nf] = mfma16(a[mf][0], b[nf][1], acc[mf][nf]);
          acc[mf][nf] = mfma16(a[mf][1], b[nf][0], acc[mf][nf]);
        }
    }
    __syncthreads();
  }

  const size_t planeV = (size_t)BB * HH * 64 * SS;
#pragma unroll
  for (int nf = 0; nf < 2; ++nf) {
    int gcol = n0 + wn * 32 + nf * 16 + lm;
    float bj = bias[gcol];
#pragma unroll
    for (int mf = 0; mf < 4; ++mf) {
      int grow0 = m0 + wm * 64 + mf * 16 + akg * 4;
      if (EPI == 0) {
#pragma unroll
        for (int r = 0; r < 4; ++r)
          Cf[(size_t)(grow0 + r) * 1024 + gcol] = acc[mf][nf][r] + bj;
      } else {
        int b_ = grow0 >> 11, t = grow0 & 2047;
        int hh = gcol >> 6, dk = gcol & 63;
        size_t ad = ((size_t)(b_ * HH + hh) * 64 + dk) * (size_t)SS + t;
        u16x4 h4, l4;
#pragma unroll
        for (int r = 0; r < 4; ++r) {
          float x = acc[mf][nf][r] + bj;
          u16 a0 = f2bf(x);
          h4[r] = a0;
          l4[r] = f2bf(x - bf2f(a0));
        }
        *reinterpret_cast<u16x4*>(Cs + ad) = h4;
        *reinterpret_cast<u16x4*>(Cs + planeV + ad) = l4;
      }
    }
  }
}

// ---------------------------------------------------------------------------
// Kernel 6: flash attention via split-bf16 MFMA.  40 KB LDS -> 4 blocks/CU.
// Q staged through the K buffer (dead after prologue reg loads).
// Epilogue writes Og as 2-way bf16 split planes (feeds out-proj MFMA GEMM).
// ---------------------------------------------------------------------------
__global__ __launch_bounds__(256, 4) void flash_mfma_kernel(
    const u16* __restrict__ QpS, const u16* __restrict__ qS,
    const u16* __restrict__ vts, u16* __restrict__ Oghi,
    u16* __restrict__ Oglo) {
  __shared__ u16 KPs[3][4096];   // Q staging -> K splits; [0..1] reused as P (24 KB)
  __shared__ u16 Vs[2][4096];    // V splits [d][t], swizzled (16 KB)
  const int tid = threadIdx.x;
  const int l = tid & 63;
  const int w = tid >> 6;
  const int lm = l & 15;
  const int akg = l >> 4;
  const int s0 = blockIdx.x * 64;
  const int bh = blockIdx.y;
  const size_t planeQ = (size_t)BB * HH * SS * 64;
  const u16* Qb = QpS + (size_t)bh * SS * 64;
  const u16* Kb = qS  + (size_t)bh * SS * 64;
  const u16* Vb = vts + (size_t)bh * 64 * SS;

  // prologue: stage Qp tile (3 planes) through KPs, pull to registers
#pragma unroll
  for (int p = 0; p < 3; ++p)
#pragma unroll
    for (int it = 0; it < 2; ++it) {
      int f = it * 256 + tid;
      int row = f >> 3, ch = f & 7;
      ushort8 vv = *reinterpret_cast<const ushort8*>(
          Qb + p * planeQ + (size_t)(s0 + row) * 64 + ch * 8);
      *reinterpret_cast<ushort8*>(&KPs[p][SWI(row, ch)]) = vv;
    }
  __syncthreads();
  short8 qa[3][2];
  {
    int arow = w * 16 + lm;
#pragma unroll
    for (int p = 0; p < 3; ++p)
#pragma unroll
      for (int ks = 0; ks < 2; ++ks)
        qa[p][ks] = *reinterpret_cast<const short8*>(&KPs[p][SWI(arow, ks * 4 + akg)]);
  }
  __syncthreads();   // all qa reads done before K staging overwrites KPs

  float mrun[4], lrun[4];
  f32x4 O[4];
  const f32x4 zero4 = {0.f, 0.f, 0.f, 0.f};
#pragma unroll
  for (int r = 0; r < 4; ++r) { mrun[r] = -INFINITY; lrun[r] = 0.f; O[r] = zero4; }

  for (int t0 = 0; t0 < SS; t0 += 64) {
    // stage K (3 planes) + V (2 planes)
#pragma unroll
    for (int p = 0; p < 3; ++p)
#pragma unroll
      for (int it = 0; it < 2; ++it) {
        int f = it * 256 + tid;
        int row = f >> 3, ch = f & 7;
        ushort8 vv = *reinterpret_cast<const ushort8*>(
            Kb + p * planeQ + (size_t)(t0 + row) * 64 + ch * 8);
        *reinterpret_cast<ushort8*>(&KPs[p][SWI(row, ch)]) = vv;
      }
#pragma unroll
    for (int p = 0; p < 2; ++p)
#pragma unroll
      for (int it = 0; it < 2; ++it) {
        int f = it * 256 + tid;
        int row = f >> 3, ch = f & 7;   // row = d
        ushort8 vv = *reinterpret_cast<const ushort8*>(
            Vb + p * planeQ + (size_t)row * SS + t0 + ch * 8);
        *reinterpret_cast<ushort8*>(&Vs[p][SWI(row, ch)]) = vv;
      }
    __syncthreads();

    // S = Qp q^T, 8 split terms (fp32-accurate logits)
    f32x4 S[4];
#pragma unroll
    for (int ct = 0; ct < 4; ++ct) {
      int brow = ct * 16 + lm;
      short8 kb[3][2];
#pragma unroll
      for (int p = 0; p < 3; ++p)
#pragma unroll
        for (int ks = 0; ks < 2; ++ks)
          kb[p][ks] = *reinterpret_cast<const short8*>(&KPs[p][SWI(brow, ks * 4 + akg)]);
      f32x4 d = zero4;
#pragma unroll
      for (int ks = 0; ks < 2; ++ks) {
        d = mfma16(qa[0][ks], kb[0][ks], d);
        d = mfma16(qa[0][ks], kb[1][ks], d);
        d = mfma16(qa[1][ks], kb[0][ks], d);
        d = mfma16(qa[0][ks], kb[2][ks], d);
        d = mfma16(qa[1][ks], kb[1][ks], d);
        d = mfma16(qa[2][ks], kb[0][ks], d);
        d = mfma16(qa[1][ks], kb[2][ks], d);
        d = mfma16(qa[2][ks], kb[1][ks], d);
      }
      S[ct] = d;
    }
    __syncthreads();   // all K reads complete; KPs[0..1] become P planes

    // online softmax; D layout: row=(l>>4)*4+r, col=l&15
    float fac[4];
#pragma unroll
    for (int r = 0; r < 4; ++r) {
      float v0 = S[0][r], v1 = S[1][r], v2 = S[2][r], v3 = S[3][r];
      float tmax = fmaxf(fmaxf(v0, v1), fmaxf(v2, v3));
#pragma unroll
      for (int m = 1; m < 16; m <<= 1) tmax = fmaxf(tmax, __shfl_xor(tmax, m, 16));
      float mnew = fmaxf(mrun[r], tmax);
      fac[r] = __expf(mrun[r] - mnew);
      mrun[r] = mnew;
      float pv[4];
      pv[0] = __expf(v0 - mnew); pv[1] = __expf(v1 - mnew);
      pv[2] = __expf(v2 - mnew); pv[3] = __expf(v3 - mnew);
      float ts = (pv[0] + pv[1]) + (pv[2] + pv[3]);
#pragma unroll
      for (int m = 1; m < 16; m <<= 1) ts += __shfl_xor(ts, m, 16);
      lrun[r] = lrun[r] * fac[r] + ts;
      int prow = w * 16 + akg * 4 + r;
      int chb = lm >> 3;
      int e = l & 7;
#pragma unroll
      for (int ct = 0; ct < 4; ++ct) {
        int idx = SWI(prow, ct * 2 + chb) + e;
        u16 hi = f2bf(pv[ct]);
        KPs[0][idx] = hi;
        KPs[1][idx] = f2bf(pv[ct] - bf2f(hi));
      }
    }
#pragma unroll
    for (int dt = 0; dt < 4; ++dt) {
      f32x4 o = O[dt];
      o[0] *= fac[0]; o[1] *= fac[1]; o[2] *= fac[2]; o[3] *= fac[3];
      O[dt] = o;
    }
    // P rows [16w,16w+16) written & read only by wave w -> in-wave ordering ok

    short8 pa[2][2];
    {
      int arow = w * 16 + lm;
#pragma unroll
      for (int p = 0; p < 2; ++p)
#pragma unroll
        for (int ks = 0; ks < 2; ++ks)
          pa[p][ks] = *reinterpret_cast<const short8*>(&KPs[p][SWI(arow, ks * 4 + akg)]);
    }
#pragma unroll
    for (int dt = 0; dt < 4; ++dt) {
      int brow = dt * 16 + lm;
#pragma unroll
      for (int ks = 0; ks < 2; ++ks) {
        short8 v0 = *reinterpret_cast<const short8*>(&Vs[0][SWI(brow, ks * 4 + akg)]);
        short8 v1 = *reinterpret_cast<const short8*>(&Vs[1][SWI(brow, ks * 4 + akg)]);
        O[dt] = mfma16(pa[0][ks], v0, O[dt]);
        O[dt] = mfma16(pa[0][ks], v1, O[dt]);
        O[dt] = mfma16(pa[1][ks], v0, O[dt]);
      }
    }
    __syncthreads();   // PV + P reads done; safe to restage next tile
  }

  // epilogue: normalize, write Og as 2-way bf16 split planes, concat layout
  const int b = bh >> 4, h = bh & 15;
  const size_t obase = ((size_t)b * SS + s0) * DD + h * 64;
#pragma unroll
  for (int r = 0; r < 4; ++r) {
    float rl = 1.f / lrun[r];
    int orow = w * 16 + akg * 4 + r;
#pragma unroll
    for (int dt = 0; dt < 4; ++dt) {
      float val = O[dt][r] * rl;
      u16 a0 = f2bf(val);
      size_t ad = obase + (size_t)orow * DD + dt * 16 + lm;
      Oghi[ad] = a0;
      Oglo[ad] = f2bf(val - bf2f(a0));
    }
  }
}

// ---------------------------------------------------------------------------
extern "C" void kernel_launch(void* const* d_in, const int* in_sizes, int n_in,
                              void* d_out, int out_size, void* d_ws, size_t ws_size,
                              hipStream_t stream) {
  (void)in_sizes; (void)n_in; (void)out_size; (void)ws_size;
  const float* q   = (const float*)d_in[0];
  // d_in[1] (k) unused by the reference forward
  const float* v   = (const float*)d_in[2];
  const float* Wv  = (const float*)d_in[3];
  const float* bv  = (const float*)d_in[4];
  const float* WA  = (const float*)d_in[5];
  const float* WA2 = (const float*)d_in[6];
  const float* Wo  = (const float*)d_in[7];
  const float* bo  = (const float*)d_in[8];
  float* out = (float*)d_out;

  // ws layout (~92.7 MB):
  //   Mm 256KB | QpS 25.2MB | qS 25.2MB | vts 16.8MB |
  //   vsp (v splits -> reused as Og splits) 16.8MB | Wvt 4.2MB | Wot 4.2MB
  const size_t planeQ = (size_t)BB * HH * SS * 64;   // 4,194,304 elems
  const size_t NK = (size_t)1024 * 1024;
  char* p = (char*)d_ws;
  float* Mm = (float*)p;        p += (1 << 18);
  u16* QpS  = (u16*)p;          p += 3 * planeQ * sizeof(u16);
  u16* qS   = (u16*)p;          p += 3 * planeQ * sizeof(u16);
  u16* vts  = (u16*)p;          p += 2 * planeQ * sizeof(u16);
  u16* vsp  = (u16*)p;          p += 2 * planeQ * sizeof(u16);   // also Og splits
  u16* Wvt  = (u16*)p;          p += 2 * NK * sizeof(u16);
  u16* Wot  = (u16*)p;          p += 2 * NK * sizeof(u16);

  split2_kernel<<<dim3(2048), dim3(256), 0, stream>>>(v, vsp, vsp + planeQ);
  split_tr_kernel<<<dim3(16, 16), dim3(256), 0, stream>>>(Wv, Wvt, Wvt + NK);
  split_tr_kernel<<<dim3(16, 16), dim3(256), 0, stream>>>(Wo, Wot, Wot + NK);
  prep_M_kernel<<<dim3(HH), dim3(256), 0, stream>>>(WA, WA2, Mm);
  qp_split_kernel<<<dim3(SS / 64, BB * HH), dim3(256), 0, stream>>>(q, Mm, QpS, qS);
  // vp = v @ Wv + bv  ->  vts transposed split planes
  gemm_mfma_kernel<1><<<dim3(16, 32), dim3(256), 0, stream>>>(
      vsp, vsp + planeQ, Wvt, Wvt + NK, bv, nullptr, vts);
  // flash: writes Og splits into vsp (v splits are dead now)
  flash_mfma_kernel<<<dim3(SS / 64, BB * HH), dim3(256), 0, stream>>>(
      QpS, qS, vts, vsp, vsp + planeQ);
  // out = Og @ Wo + bo
  gemm_mfma_kernel<0><<<dim3(16, 32), dim3(256), 0, stream>>>(
      vsp, vsp + planeQ, Wot, Wot + NK, bo, out, nullptr);
}